// Round 6
// baseline (468.707 us; speedup 1.0000x reference)
//
#include <hip/hip_runtime.h>
#include <hip/hip_bf16.h>

// GlobalFilter: y = irfft2(rfft2(x, ortho) * W, ortho) over axes (1,2)
// == per-channel 14x14 circular conv with real kernel k_c = ifft2(M_c):
//   k_c[p,q] = (1/196) * sum_{u<14,v<8} c_v*(Wr*cos(th) - Wi*sin(th)),
//   th = 2*pi*(u*p+v*q)/14, c_v = 1 for v in {0,7} else 2.
//
// v6: 448-thread blocks (7 waves, one per output row-pair) per (batch, 64-ch
// group) -> sibling waves share x via same-CU L1/L2 (kills R5's 7x HBM
// re-read). No LDS in conv (LDS operands get re-read per FMA by hipcc;
// global->reg stays resident, R5: VGPR=128). Row-at-a-time: output rows
// (h0,h0+1) both consume x[r] against k-rows d0=(h0-r)%14, d0+1.
// A/B retained: batches 0..63 f32 fmac, 64..127 pkrtz+v_pk_fma_f16.

typedef _Float16 h2 __attribute__((ext_vector_type(2)));

#define CC 768

// ---------------- Kernel A: plain spatial kernels k[196][768] f32 ----------------
// grid (12 cgroups, 14 p), 896 threads = 14 q x 64 ch.
__global__ __launch_bounds__(896) void gf_build_k(const float* __restrict__ wg,
                                                  float* __restrict__ kbuf) {
    __shared__ float ws[112 * 128];        // [uv][cl][ri], pre-scaled by cv/196
    __shared__ float ct[14], st[14];
    int t = threadIdx.x;
    int c0 = blockIdx.x * 64;
    int p  = blockIdx.y;
    if (t < 14) {
        float ang = 6.283185307179586f * (float)t / 14.0f;
        ct[t] = cosf(ang);
        st[t] = sinf(ang);
    }
    #pragma unroll
    for (int j = 0; j < 16; ++j) {
        int f = t + j * 896;               // 0..14335
        int uv = f >> 7;
        int v = uv & 7;
        float scale = (v == 0 || v == 7) ? (1.0f / 196.0f) : (2.0f / 196.0f);
        ws[f] = wg[(size_t)uv * 1536 + (size_t)c0 * 2 + (f & 127)] * scale;
    }
    __syncthreads();

    int q = t >> 6, cl = t & 63;
    float a = 0.f;
    int up = 0;                            // (u*p) % 14
    #pragma unroll
    for (int u = 0; u < 14; ++u) {
        int r = up;                        // (u*p + v*q) % 14
        #pragma unroll
        for (int v = 0; v < 8; ++v) {
            float wr = ws[(u * 8 + v) * 128 + cl * 2];
            float wi = ws[(u * 8 + v) * 128 + cl * 2 + 1];
            a += wr * ct[r] - wi * st[r];
            r += q; if (r >= 14) r -= 14;
        }
        up += p; if (up >= 14) up -= 14;
    }
    kbuf[(size_t)(p * 14 + q) * CC + c0 + cl] = a;
}

// ---------------- Kernel B: depthwise circular conv, register-pipelined ----------------
// grid (12 cgroups, 64 batches), 448 threads. No LDS, no barriers.
template<bool USE_F16>
__global__ __launch_bounds__(448, 4) void gf_conv6(const float* __restrict__ x,
                                                   const float* __restrict__ kbuf,
                                                   float* __restrict__ y, int b_base) {
    int b  = b_base + blockIdx.y;
    int c0 = blockIdx.x * 64;
    int t  = threadIdx.x;
    int cl = t & 63;                       // lane = channel
    int g  = t >> 6;                       // wave id 0..6
    int h0 = 2 * g;                        // output rows h0, h0+1

    const float* xb = x + (size_t)b * 196 * CC + c0 + cl;
    const float* kb = kbuf + c0 + cl;

    float xr[2][14];                       // x row cur/next
    float kr[3][14];                       // k rows: prev / cur / next (rotation)

    // prologue: x[0]; kr[0]=k[h0+1] (prev), kr[1]=k[h0] (cur). h0+1 <= 13, no wrap.
    #pragma unroll
    for (int w = 0; w < 14; ++w) xr[0][w] = xb[w * CC];
    #pragma unroll
    for (int q = 0; q < 14; ++q) kr[0][q] = kb[((h0 + 1) * 14 + q) * CC];
    #pragma unroll
    for (int q = 0; q < 14; ++q) kr[1][q] = kb[(h0 * 14 + q) * CC];

    float acc0[14], acc1[14];              // f32 path
    h2 acc[14];                            // f16 path
    if constexpr (USE_F16) {
        #pragma unroll
        for (int w = 0; w < 14; ++w) { acc[w].x = (_Float16)0.f; acc[w].y = (_Float16)0.f; }
    } else {
        #pragma unroll
        for (int w = 0; w < 14; ++w) { acc0[w] = 0.f; acc1[w] = 0.f; }
    }

    int kd0 = h0;                          // current d0 = (h0 - r) mod 14
    #pragma unroll
    for (int r = 0; r < 14; ++r) {
        const int xc = r & 1, xn = xc ^ 1;
        const int sprev = r % 3, scur = (r + 1) % 3, snext = (r + 2) % 3;  // static

        // prefetch next x row + next k row (hidden under the 392-fma chain)
        if (r < 13) {
            #pragma unroll
            for (int w = 0; w < 14; ++w) xr[xn][w] = xb[((r + 1) * 14 + w) * CC];
            int kn = (kd0 == 0) ? 13 : kd0 - 1;
            #pragma unroll
            for (int q = 0; q < 14; ++q) kr[snext][q] = kb[(kn * 14 + q) * CC];
            kd0 = kn;
        }

        if constexpr (USE_F16) {
            h2 xh[14], kp[14];
            #pragma unroll
            for (int w = 0; w < 14; ++w)
                xh[w] = __builtin_bit_cast(h2, __builtin_amdgcn_cvt_pkrtz(xr[xc][w], xr[xc][w]));
            #pragma unroll
            for (int q = 0; q < 14; ++q)   // (.x = k[d0], .y = k[d0+1])
                kp[q] = __builtin_bit_cast(h2, __builtin_amdgcn_cvt_pkrtz(kr[scur][q], kr[sprev][q]));
            #pragma unroll
            for (int q = 0; q < 14; ++q) {
                #pragma unroll
                for (int w = 0; w < 14; ++w) {
                    int src = w - q; if (src < 0) src += 14;
                    acc[w] = kp[q] * xh[src] + acc[w];     // v_pk_fma_f16
                }
            }
        } else {
            #pragma unroll
            for (int q = 0; q < 14; ++q) {
                float k0 = kr[scur][q];    // k[d0]   -> row h0
                float k1 = kr[sprev][q];   // k[d0+1] -> row h0+1
                #pragma unroll
                for (int w = 0; w < 14; ++w) {
                    int src = w - q; if (src < 0) src += 14;
                    acc0[w] += k0 * xr[xc][src];
                    acc1[w] += k1 * xr[xc][src];
                }
            }
        }
    }

    float* yb = y + (size_t)b * 196 * CC + c0 + cl;
    #pragma unroll
    for (int w = 0; w < 14; ++w) {
        if constexpr (USE_F16) {
            yb[(h0 * 14 + w) * CC]       = (float)acc[w].x;
            yb[((h0 + 1) * 14 + w) * CC] = (float)acc[w].y;
        } else {
            yb[(h0 * 14 + w) * CC]       = acc0[w];
            yb[((h0 + 1) * 14 + w) * CC] = acc1[w];
        }
    }
}

extern "C" void kernel_launch(void* const* d_in, const int* in_sizes, int n_in,
                              void* d_out, int out_size, void* d_ws, size_t ws_size,
                              hipStream_t stream) {
    const float* x = (const float*)d_in[0];
    const float* w = (const float*)d_in[1];
    float* y = (float*)d_out;
    float* kbuf = (float*)d_ws;            // 196*768*4 = 602,112 B

    gf_build_k<<<dim3(12, 14), dim3(896), 0, stream>>>(w, kbuf);

    dim3 grid(12, 64);                     // cgroup, batch-half
    gf_conv6<false><<<grid, dim3(448), 0, stream>>>(x, kbuf, y, 0);   // f32 fmac half
    gf_conv6<true ><<<grid, dim3(448), 0, stream>>>(x, kbuf, y, 64);  // pk_fma_f16 half
}

// Round 7
// 197.075 us; speedup vs baseline: 2.3783x; 2.3783x over previous
//
#include <hip/hip_runtime.h>
#include <hip/hip_bf16.h>

// GlobalFilter: y = irfft2(rfft2(x, ortho) * W, ortho) over axes (1,2)
// == per-channel 14x14 circular conv with real kernel k_c = ifft2(M_c):
//   k_c[p,q] = (1/196) * sum_{u<14,v<8} c_v*(Wr*cos(th) - Wi*sin(th)),
//   th = 2*pi*(u*p+v*q)/14, c_v = 1 for v in {0,7} else 2.
//
// v7: 448-thread blocks (7 waves = 7 output row-pairs) per (batch, 64ch);
// x shared across waves via L1/L2. All operands register-resident, no LDS,
// no barriers, NO launch_bounds min-occupancy arg (R6: "(448,4)" -> 64-VGPR
// cap -> full spill -> 995 MB scratch writes, 4.4x slower).
// Kernel A pre-packs kp[d][q] = half2(k[d][q], k[(d+1)%14][q]) so conv keeps
// only one packed k-row (+prefetch) live. A/B: batches 0..63 f32 fmac
// (unpack kp), 64..127 v_pk_fma_f16 -- clean pk-f16 rate measurement.

typedef _Float16 h2 __attribute__((ext_vector_type(2)));

#define CC 768

// ---------------- Kernel A: packed spatial kernels kp[14][14][768] u32 ----------------
// grid (12 cgroups, 14 d), 896 threads = 14 q x 64 ch.
// kp[d][q][c] = half2( k[d][q][c], k[(d+1)%14][q][c] )
__global__ __launch_bounds__(896) void gf_build_kp(const float* __restrict__ wg,
                                                   unsigned int* __restrict__ kp) {
    __shared__ float ws[112 * 128];        // [uv][cl][ri], pre-scaled by cv/196
    __shared__ float ct[14], st[14];
    int t = threadIdx.x;
    int c0 = blockIdx.x * 64;
    int p  = blockIdx.y;                   // d
    if (t < 14) {
        float ang = 6.283185307179586f * (float)t / 14.0f;
        ct[t] = cosf(ang);
        st[t] = sinf(ang);
    }
    #pragma unroll
    for (int j = 0; j < 16; ++j) {
        int f = t + j * 896;               // 0..14335
        int uv = f >> 7;
        int v = uv & 7;
        float scale = (v == 0 || v == 7) ? (1.0f / 196.0f) : (2.0f / 196.0f);
        ws[f] = wg[(size_t)uv * 1536 + (size_t)c0 * 2 + (f & 127)] * scale;
    }
    __syncthreads();

    int q = t >> 6, cl = t & 63;
    int p1 = (p + 1) % 14;                 // d+1
    float a0 = 0.f, a1 = 0.f;
    int up0 = 0, up1 = 0;
    #pragma unroll
    for (int u = 0; u < 14; ++u) {
        int r0 = up0, r1 = up1;
        #pragma unroll
        for (int v = 0; v < 8; ++v) {
            float wr = ws[(u * 8 + v) * 128 + cl * 2];
            float wi = ws[(u * 8 + v) * 128 + cl * 2 + 1];
            a0 += wr * ct[r0] - wi * st[r0];
            a1 += wr * ct[r1] - wi * st[r1];
            r0 += q; if (r0 >= 14) r0 -= 14;
            r1 += q; if (r1 >= 14) r1 -= 14;
        }
        up0 += p;  if (up0 >= 14) up0 -= 14;
        up1 += p1; if (up1 >= 14) up1 -= 14;
    }
    h2 pk; pk.x = (_Float16)a0; pk.y = (_Float16)a1;
    kp[(size_t)(p * 14 + q) * CC + c0 + cl] = __builtin_bit_cast(unsigned int, pk);
}

// ---------------- Kernel B: depthwise circular conv, register-pipelined ----------------
// grid (12 cgroups, 64 batches), 448 threads, no LDS/barriers.
template<bool USE_F16>
__global__ __launch_bounds__(448) void gf_conv7(const float* __restrict__ x,
                                                const unsigned int* __restrict__ kp,
                                                float* __restrict__ y, int b_base) {
    int b  = b_base + blockIdx.y;
    int c0 = blockIdx.x * 64;
    int t  = threadIdx.x;
    int cl = t & 63;                       // lane = channel
    int g  = t >> 6;                       // wave id 0..6
    int h0 = 2 * g;                        // output rows h0, h0+1

    const float* xb = x + (size_t)b * 196 * CC + c0 + cl;
    const unsigned int* kb = kp + c0 + cl;

    float        xf[2][14];                // x row cur/next (f32)
    unsigned int kr[2][14];                // packed k row cur/next

    #pragma unroll
    for (int w = 0; w < 14; ++w) xf[0][w] = xb[w * CC];
    #pragma unroll
    for (int q = 0; q < 14; ++q) kr[0][q] = kb[(h0 * 14 + q) * CC];

    float acc0[14], acc1[14];              // f32 path
    h2 acc[14];                            // f16 path
    if constexpr (USE_F16) {
        #pragma unroll
        for (int w = 0; w < 14; ++w) { acc[w].x = (_Float16)0.f; acc[w].y = (_Float16)0.f; }
    } else {
        #pragma unroll
        for (int w = 0; w < 14; ++w) { acc0[w] = 0.f; acc1[w] = 0.f; }
    }

    int d0 = h0;                           // k-row index for this r-step
    #pragma unroll
    for (int r = 0; r < 14; ++r) {
        const int xc = r & 1, xn = xc ^ 1; // static after unroll

        if (r < 13) {                      // prefetch next x row + next packed k row
            #pragma unroll
            for (int w = 0; w < 14; ++w) xf[xn][w] = xb[((r + 1) * 14 + w) * CC];
            int dn = (d0 == 0) ? 13 : d0 - 1;
            #pragma unroll
            for (int q = 0; q < 14; ++q) kr[xn][q] = kb[(dn * 14 + q) * CC];
            d0 = dn;
        }

        if constexpr (USE_F16) {
            h2 xh[14];
            #pragma unroll
            for (int w = 0; w < 14; ++w)
                xh[w] = __builtin_bit_cast(h2, __builtin_amdgcn_cvt_pkrtz(xf[xc][w], xf[xc][w]));
            #pragma unroll
            for (int q = 0; q < 14; ++q) {
                h2 kv = __builtin_bit_cast(h2, kr[xc][q]);
                #pragma unroll
                for (int w = 0; w < 14; ++w) {
                    int src = w - q; if (src < 0) src += 14;
                    acc[w] = kv * xh[src] + acc[w];        // v_pk_fma_f16
                }
            }
        } else {
            #pragma unroll
            for (int q = 0; q < 14; ++q) {
                h2 kv = __builtin_bit_cast(h2, kr[xc][q]);
                float k0 = (float)kv.x;    // k[d0]   -> row h0
                float k1 = (float)kv.y;    // k[d0+1] -> row h0+1
                #pragma unroll
                for (int w = 0; w < 14; ++w) {
                    int src = w - q; if (src < 0) src += 14;
                    acc0[w] += k0 * xf[xc][src];
                    acc1[w] += k1 * xf[xc][src];
                }
            }
        }
    }

    float* yb = y + (size_t)b * 196 * CC + c0 + cl;
    #pragma unroll
    for (int w = 0; w < 14; ++w) {
        if constexpr (USE_F16) {
            yb[(h0 * 14 + w) * CC]       = (float)acc[w].x;
            yb[((h0 + 1) * 14 + w) * CC] = (float)acc[w].y;
        } else {
            yb[(h0 * 14 + w) * CC]       = acc0[w];
            yb[((h0 + 1) * 14 + w) * CC] = acc1[w];
        }
    }
}

extern "C" void kernel_launch(void* const* d_in, const int* in_sizes, int n_in,
                              void* d_out, int out_size, void* d_ws, size_t ws_size,
                              hipStream_t stream) {
    const float* x = (const float*)d_in[0];
    const float* w = (const float*)d_in[1];
    float* y = (float*)d_out;
    unsigned int* kbuf = (unsigned int*)d_ws;   // 196*768*4 = 602,112 B

    gf_build_kp<<<dim3(12, 14), dim3(896), 0, stream>>>(w, kbuf);

    dim3 grid(12, 64);                          // cgroup, batch-half
    gf_conv7<false><<<grid, dim3(448), 0, stream>>>(x, kbuf, y, 0);   // f32 fmac half
    gf_conv7<true ><<<grid, dim3(448), 0, stream>>>(x, kbuf, y, 64);  // pk_fma_f16 half
}